// Round 3
// baseline (10134.514 us; speedup 1.0000x reference)
//
#include <hip/hip_runtime.h>
#include <math.h>

#define BATCH 512
#define MAXLEN 80
#define LATENT 10
#define HID 64
#define NSTEPS 100
#define DT 0.01f

#define F10(M) M(0) M(1) M(2) M(3) M(4) M(5) M(6) M(7) M(8) M(9)

// per-d declarations
#define DECL(d) float mu##d, is##d, cv##d, cw##d, xt##d, er##d, ac##d, nz##d, cu##d, rb2_##d;

#define SETUP(d) { \
    float zm  = z_mean[base + d]; \
    float zmp = lp ? z_mean[basep + d] : 0.0f; \
    float zv  = z_log_var[base + d]; \
    float zvp = lp ? z_log_var[basep + d] : 0.0f; \
    float mx  = fmaxf(zv, zvp); \
    float sg  = mx + log1pf(expf(-fabsf(zv - zvp))); \
    float sd  = expf(0.5f * sg); \
    mu##d = zm - zmp; \
    is##d = 1.0f / sg; \
    cv##d = 0.5f * DT * sd * sd; \
    cw##d = sd * sqrt_dt; \
    xt##d = mu##d; \
    er##d = 0.0f; \
    rb2_##d = b2[d]; }

#define LDNZ(ptr) { \
    const float2* p2_ = (const float2*)(ptr); \
    float2 v0_ = p2_[0], v1_ = p2_[1], v2_ = p2_[2], v3_ = p2_[3], v4_ = p2_[4]; \
    nz0 = v0_.x; nz1 = v0_.y; nz2 = v1_.x; nz3 = v1_.y; nz4 = v2_.x; \
    nz5 = v2_.y; nz6 = v3_.x; nz7 = v3_.y; nz8 = v4_.x; nz9 = v4_.y; }

#define CPY(d) cu##d = nz##d;
#define ACC0(d) ac##d = rb2_##d;

#define W1K(k) { \
    float4 wA = *(const float4*)&sW1[k][j0]; \
    float4 wB = *(const float4*)&sW1[k][j0 + 4]; \
    h0 = fmaf(xt##k, wA.x, h0); h1 = fmaf(xt##k, wA.y, h1); \
    h2 = fmaf(xt##k, wA.z, h2); h3 = fmaf(xt##k, wA.w, h3); \
    h4 = fmaf(xt##k, wB.x, h4); h5 = fmaf(xt##k, wB.y, h5); \
    h6 = fmaf(xt##k, wB.z, h6); h7 = fmaf(xt##k, wB.w, h7); }

#define W2D(d) { \
    float4 wA = *(const float4*)&sW2T[d][j0]; \
    float4 wB = *(const float4*)&sW2T[d][j0 + 4]; \
    ac##d = fmaf(h0, wA.x, ac##d); ac##d = fmaf(h1, wA.y, ac##d); \
    ac##d = fmaf(h2, wA.z, ac##d); ac##d = fmaf(h3, wA.w, ac##d); \
    ac##d = fmaf(h4, wB.x, ac##d); ac##d = fmaf(h5, wB.y, ac##d); \
    ac##d = fmaf(h6, wB.z, ac##d); ac##d = fmaf(h7, wB.w, ac##d); }

#define UPD(d) { \
    float ld_ = (mu##d - xt##d) * is##d; \
    float df_ = ld_ - ac##d; \
    er##d = fmaf(df_, df_, er##d); \
    xt##d = fmaf(cw##d, cu##d, fmaf(cv##d, ac##d, fmaf(mu##d, DT, xt##d))); }

#define ST(d) o0[d] = xt##d; o1[d] = er##d * (1.0f / NSTEPS);

__global__ __launch_bounds__(64) void vae_sde_kernel(
    const float* __restrict__ z_mean, const float* __restrict__ z_log_var,
    const float* __restrict__ W1, const float* __restrict__ b1,
    const float* __restrict__ W2, const float* __restrict__ b2,
    const float* __restrict__ noise, float* __restrict__ out)
{
    __shared__ float sW1[11][HID];
    __shared__ float sb1[HID];
    __shared__ float sW2T[LATENT][HID];

    for (int i = threadIdx.x; i < 11 * HID; i += 64) sW1[i >> 6][i & 63] = W1[i];
    sb1[threadIdx.x] = b1[threadIdx.x];
    for (int i = threadIdx.x; i < LATENT * HID; i += 64) {
        int d = i >> 6, j = i & 63;
        sW2T[d][j] = W2[j * LATENT + d];
    }
    __syncthreads();

    const int c  = blockIdx.x * 64 + threadIdx.x;   // chain id
    const int l  = c >> 9;                          // position 0..79
    const int bb = c & 511;                         // batch 0..511

    const int base  = (bb * MAXLEN + l) * LATENT;
    const int basep = base - LATENT;
    const bool lp = (l > 0);
    const float sqrt_dt = sqrtf(DT);

    F10(DECL)

    F10(SETUP)

    const float* nbase = noise + (size_t)l * (NSTEPS * BATCH * LATENT) + bb * LATENT;
    LDNZ(nbase)

    #pragma unroll 1
    for (int s = 0; s < NSTEPS; ++s) {
        F10(CPY)
        if (s + 1 < NSTEPS) {
            LDNZ(nbase + (size_t)(s + 1) * (BATCH * LATENT))
        }
        const float tt = (float)(l + s) * DT;
        F10(ACC0)

        #pragma unroll
        for (int j0 = 0; j0 < HID; j0 += 8) {
            float4 bA = *(const float4*)&sb1[j0];
            float4 bB = *(const float4*)&sb1[j0 + 4];
            float h0 = bA.x, h1 = bA.y, h2 = bA.z, h3 = bA.w;
            float h4 = bB.x, h5 = bB.y, h6 = bB.z, h7 = bB.w;

            F10(W1K)

            {
                float4 wA = *(const float4*)&sW1[10][j0];
                float4 wB = *(const float4*)&sW1[10][j0 + 4];
                h0 = fmaxf(fmaf(tt, wA.x, h0), 0.0f);
                h1 = fmaxf(fmaf(tt, wA.y, h1), 0.0f);
                h2 = fmaxf(fmaf(tt, wA.z, h2), 0.0f);
                h3 = fmaxf(fmaf(tt, wA.w, h3), 0.0f);
                h4 = fmaxf(fmaf(tt, wB.x, h4), 0.0f);
                h5 = fmaxf(fmaf(tt, wB.y, h5), 0.0f);
                h6 = fmaxf(fmaf(tt, wB.z, h6), 0.0f);
                h7 = fmaxf(fmaf(tt, wB.w, h7), 0.0f);
            }

            F10(W2D)
        }

        F10(UPD)
    }

    float* o0 = out + base;
    float* o1 = out + (BATCH * MAXLEN * LATENT) + base;
    F10(ST)
}

extern "C" void kernel_launch(void* const* d_in, const int* in_sizes, int n_in,
                              void* d_out, int out_size, void* d_ws, size_t ws_size,
                              hipStream_t stream) {
    const float* z_mean    = (const float*)d_in[0];
    const float* z_log_var = (const float*)d_in[1];
    const float* W1 = (const float*)d_in[2];
    const float* b1 = (const float*)d_in[3];
    const float* W2 = (const float*)d_in[4];
    const float* b2 = (const float*)d_in[5];
    const float* noise = (const float*)d_in[6];
    float* out = (float*)d_out;

    vae_sde_kernel<<<dim3(640), dim3(64), 0, stream>>>(
        z_mean, z_log_var, W1, b1, W2, b2, noise, out);
}

// Round 4
// 766.745 us; speedup vs baseline: 13.2176x; 13.2176x over previous
//
#include <hip/hip_runtime.h>
#include <math.h>

#define BATCH 512
#define MAXLEN 80
#define LATENT 10
#define HID 64
#define NSTEPS 100
#define DT 0.01f

#define F10(M) M(0) M(1) M(2) M(3) M(4) M(5) M(6) M(7) M(8) M(9)

#define DECL(d) float mu##d, is##d, cv##d, cw##d, xt##d, er##d, ac##d, nz##d, cu##d, rb2_##d;

#define SETUP(d) { \
    float zm  = z_mean[base + d]; \
    float zmp = lp ? z_mean[basep + d] : 0.0f; \
    float zv  = z_log_var[base + d]; \
    float zvp = lp ? z_log_var[basep + d] : 0.0f; \
    float mx  = fmaxf(zv, zvp); \
    float sg  = mx + log1pf(expf(-fabsf(zv - zvp))); \
    float sd  = expf(0.5f * sg); \
    mu##d = zm - zmp; \
    is##d = 1.0f / sg; \
    cv##d = 0.5f * DT * sd * sd; \
    cw##d = sd * sqrt_dt; \
    xt##d = mu##d; \
    er##d = 0.0f; \
    rb2_##d = b2[d]; }

#define LDNZ(ptr) { \
    const float2* p2_ = (const float2*)(ptr); \
    float2 v0_ = p2_[0], v1_ = p2_[1], v2_ = p2_[2], v3_ = p2_[3], v4_ = p2_[4]; \
    nz0 = v0_.x; nz1 = v0_.y; nz2 = v1_.x; nz3 = v1_.y; nz4 = v2_.x; \
    nz5 = v2_.y; nz6 = v3_.x; nz7 = v3_.y; nz8 = v4_.x; nz9 = v4_.y; }

#define CPY(d) cu##d = nz##d;
#define ACC0(d) ac##d = rb2_##d;

// weights layout in smem: W1 rows 0..10 at [k*64], b1 at [704], W2T row d at [768 + d*64]
#define W1K(k) { \
    float4 wA = *(const float4*)(wp + (k) * HID); \
    float4 wB = *(const float4*)(wp + (k) * HID + 4); \
    h0 = fmaf(xt##k, wA.x, h0); h1 = fmaf(xt##k, wA.y, h1); \
    h2 = fmaf(xt##k, wA.z, h2); h3 = fmaf(xt##k, wA.w, h3); \
    h4 = fmaf(xt##k, wB.x, h4); h5 = fmaf(xt##k, wB.y, h5); \
    h6 = fmaf(xt##k, wB.z, h6); h7 = fmaf(xt##k, wB.w, h7); }

#define W2D(d) { \
    float4 wA = *(const float4*)(wp + 12 * HID + (d) * HID); \
    float4 wB = *(const float4*)(wp + 12 * HID + (d) * HID + 4); \
    ac##d = fmaf(h0, wA.x, ac##d); ac##d = fmaf(h1, wA.y, ac##d); \
    ac##d = fmaf(h2, wA.z, ac##d); ac##d = fmaf(h3, wA.w, ac##d); \
    ac##d = fmaf(h4, wB.x, ac##d); ac##d = fmaf(h5, wB.y, ac##d); \
    ac##d = fmaf(h6, wB.z, ac##d); ac##d = fmaf(h7, wB.w, ac##d); }

#define UPD(d) { \
    float ld_ = (mu##d - xt##d) * is##d; \
    float df_ = ld_ - ac##d; \
    er##d = fmaf(df_, df_, er##d); \
    xt##d = fmaf(cw##d, cu##d, fmaf(cv##d, ac##d, fmaf(mu##d, DT, xt##d))); }

#define ST(d) o0[d] = xt##d; o1[d] = er##d * (1.0f / NSTEPS);

__global__ __launch_bounds__(64) void vae_sde_kernel(
    const float* __restrict__ z_mean, const float* __restrict__ z_log_var,
    const float* __restrict__ W1, const float* __restrict__ b1,
    const float* __restrict__ W2, const float* __restrict__ b2,
    const float* __restrict__ noise, float* __restrict__ out)
{
    __shared__ __align__(16) float smem[1408];  // 704 W1 | 64 b1 | 640 W2T

    for (int i = threadIdx.x; i < 11 * HID; i += 64) smem[i] = W1[i];
    smem[11 * HID + threadIdx.x] = b1[threadIdx.x];
    for (int i = threadIdx.x; i < LATENT * HID; i += 64) {
        int d = i >> 6, j = i & 63;
        smem[12 * HID + d * HID + j] = W2[j * LATENT + d];
    }
    __syncthreads();

    const int c  = blockIdx.x * 64 + threadIdx.x;   // chain id
    const int l  = c >> 9;                          // position 0..79
    const int bb = c & 511;                         // batch 0..511

    const int base  = (bb * MAXLEN + l) * LATENT;
    const int basep = base - LATENT;
    const bool lp = (l > 0);
    const float sqrt_dt = sqrtf(DT);

    F10(DECL)
    F10(SETUP)

    const float* nbase = noise + (size_t)l * (NSTEPS * BATCH * LATENT) + bb * LATENT;
    LDNZ(nbase)

    #pragma unroll 1
    for (int s = 0; s < NSTEPS; ++s) {
        // opaque offset: defeats LICM hoisting LDS loads out of the step loop
        int ofs0 = 0;
        asm volatile("" : "+v"(ofs0));
        const float* sm = smem + ofs0;

        F10(CPY)
        if (s + 1 < NSTEPS) {
            LDNZ(nbase + (size_t)(s + 1) * (BATCH * LATENT))
        }
        const float tt = (float)(l + s) * DT;
        F10(ACC0)

        // runtime j0 + unroll 1: every LDS address is loop-variant -> no
        // hoisting, no register-allocator meltdown (R1-R3 bug: full unroll
        // made all weight loads loop-invariant -> 500+ spilled VGPRs ->
        // 8.5 GB/launch of scratch reload traffic)
        #pragma unroll 1
        for (int j0 = 0; j0 < HID; j0 += 8) {
            const float* wp = sm + j0;
            float4 bA = *(const float4*)(wp + 11 * HID);
            float4 bB = *(const float4*)(wp + 11 * HID + 4);
            float h0 = bA.x, h1 = bA.y, h2 = bA.z, h3 = bA.w;
            float h4 = bB.x, h5 = bB.y, h6 = bB.z, h7 = bB.w;

            F10(W1K)

            {   // time feature row (k=10) + ReLU
                float4 wA = *(const float4*)(wp + 10 * HID);
                float4 wB = *(const float4*)(wp + 10 * HID + 4);
                h0 = fmaxf(fmaf(tt, wA.x, h0), 0.0f);
                h1 = fmaxf(fmaf(tt, wA.y, h1), 0.0f);
                h2 = fmaxf(fmaf(tt, wA.z, h2), 0.0f);
                h3 = fmaxf(fmaf(tt, wA.w, h3), 0.0f);
                h4 = fmaxf(fmaf(tt, wB.x, h4), 0.0f);
                h5 = fmaxf(fmaf(tt, wB.y, h5), 0.0f);
                h6 = fmaxf(fmaf(tt, wB.z, h6), 0.0f);
                h7 = fmaxf(fmaf(tt, wB.w, h7), 0.0f);
            }

            F10(W2D)
        }

        F10(UPD)
    }

    float* o0 = out + base;
    float* o1 = out + (BATCH * MAXLEN * LATENT) + base;
    F10(ST)
}

extern "C" void kernel_launch(void* const* d_in, const int* in_sizes, int n_in,
                              void* d_out, int out_size, void* d_ws, size_t ws_size,
                              hipStream_t stream) {
    const float* z_mean    = (const float*)d_in[0];
    const float* z_log_var = (const float*)d_in[1];
    const float* W1 = (const float*)d_in[2];
    const float* b1 = (const float*)d_in[3];
    const float* W2 = (const float*)d_in[4];
    const float* b2 = (const float*)d_in[5];
    const float* noise = (const float*)d_in[6];
    float* out = (float*)d_out;

    vae_sde_kernel<<<dim3(640), dim3(64), 0, stream>>>(
        z_mean, z_log_var, W1, b1, W2, b2, noise, out);
}

// Round 5
// 229.947 us; speedup vs baseline: 44.0732x; 3.3344x over previous
//
#include <hip/hip_runtime.h>
#include <math.h>

#define BATCH 512
#define MAXLEN 80
#define LATENT 10
#define HID 64
#define NSTEPS 100
#define DT 0.01f
#define OUTOFF (BATCH * MAXLEN * LATENT)

// 8 lanes per chain. Lane owns hidden units j=8*lane..8*lane+7 (weights in
// VGPRs: W1 11x8, b1 8, W2(scaled) 8x10) and output dim d=lane (+d=8,9 on
// lanes 0,1). Per step the affine xt-update is folded into one 8-lane DPP
// butterfly all-reduce (no LDS, no ds_bpermute in the loop).

__device__ __forceinline__ float dpp8_allsum(float x) {
    int t;
    t = __builtin_amdgcn_update_dpp(0, __float_as_int(x), 0xB1, 0xF, 0xF, false);  // quad_perm [1,0,3,2] : xor 1
    x += __int_as_float(t);
    t = __builtin_amdgcn_update_dpp(0, __float_as_int(x), 0x4E, 0xF, 0xF, false);  // quad_perm [2,3,0,1] : xor 2
    x += __int_as_float(t);
    t = __builtin_amdgcn_update_dpp(0, __float_as_int(x), 0x141, 0xF, 0xF, false); // row_half_mirror : other quad
    x += __int_as_float(t);
    return x;
}

#define F8(M)  M(0) M(1) M(2) M(3) M(4) M(5) M(6) M(7)

// h += xk * w1[k][0..7]
#define HK(k, xk) \
    h0 = fmaf(xk, w1a##k.x, h0); h1 = fmaf(xk, w1a##k.y, h1); \
    h2 = fmaf(xk, w1a##k.z, h2); h3 = fmaf(xk, w1a##k.w, h3); \
    h4 = fmaf(xk, w1b##k.x, h4); h5 = fmaf(xk, w1b##k.y, h5); \
    h6 = fmaf(xk, w1b##k.z, h6); h7 = fmaf(xk, w1b##k.w, h7);

// ac_d += h_q * w2c[q][d]
#define W2Q(q, hq) \
    ac0 = fmaf(hq, w2A##q.x, ac0); ac1 = fmaf(hq, w2A##q.y, ac1); \
    ac2 = fmaf(hq, w2A##q.z, ac2); ac3 = fmaf(hq, w2A##q.w, ac3); \
    ac4 = fmaf(hq, w2B##q.x, ac4); ac5 = fmaf(hq, w2B##q.y, ac5); \
    ac6 = fmaf(hq, w2B##q.z, ac6); ac7 = fmaf(hq, w2B##q.w, ac7); \
    ac8 = fmaf(hq, w2C##q.x, ac8); ac9 = fmaf(hq, w2C##q.y, ac9);

__global__ __launch_bounds__(256, 2) void vae_sde_kernel(
    const float* __restrict__ z_mean, const float* __restrict__ z_log_var,
    const float* __restrict__ W1, const float* __restrict__ b1,
    const float* __restrict__ W2, const float* __restrict__ b2,
    const float* __restrict__ noise, float* __restrict__ out)
{
    __shared__ float sMU[32][LATENT];
    __shared__ float sSG[32][LATENT];

    const int tid  = threadIdx.x;
    const int g    = blockIdx.x * 256 + tid;
    const int c    = g >> 3;          // chain id
    const int lane = tid & 7;         // sub-lane within chain
    const int cb   = tid >> 3;        // chain within block
    const int l    = c >> 9;
    const int bb   = c & 511;
    const int base = (bb * MAXLEN + l) * LATENT;
    const bool lp   = (l > 0);
    const bool has2 = (lane < 2);
    const float sqdt = sqrtf(DT);

    // ---- per-owned-d setup (primary d=lane; secondary d=8+lane on lanes 0,1)
    float mur0, is0, cw0, icv0, rb2_0, mb0, er0, xsel0;
    float mur1 = 0.f, is1 = 0.f, cw1 = 0.f, icv1 = 0.f, rb2_1 = 0.f,
          mb1 = 0.f, er1 = 0.f, xsel1 = 0.f;

    {
        const int d = lane;
        float zm  = z_mean[base + d];
        float zmp = lp ? z_mean[base - LATENT + d] : 0.f;
        float zv  = z_log_var[base + d];
        float zvp = lp ? z_log_var[base - LATENT + d] : 0.f;
        float mx  = fmaxf(zv, zvp);
        float sg  = mx + log1pf(expf(-fabsf(zv - zvp)));
        float sd  = expf(0.5f * sg);
        float cvv = 0.5f * DT * sd * sd;
        mur0 = zm - zmp; is0 = 1.f / sg; cw0 = sd * sqdt; icv0 = 1.f / cvv;
        rb2_0 = b2[d]; mb0 = fmaf(cvv, rb2_0, mur0 * DT);
        er0 = 0.f; xsel0 = mur0;
        sMU[cb][d] = mur0;
        sSG[cb][d] = sg;
    }
    if (has2) {
        const int d = 8 + lane;
        float zm  = z_mean[base + d];
        float zmp = lp ? z_mean[base - LATENT + d] : 0.f;
        float zv  = z_log_var[base + d];
        float zvp = lp ? z_log_var[base - LATENT + d] : 0.f;
        float mx  = fmaxf(zv, zvp);
        float sg  = mx + log1pf(expf(-fabsf(zv - zvp)));
        float sd  = expf(0.5f * sg);
        float cvv = 0.5f * DT * sd * sd;
        mur1 = zm - zmp; is1 = 1.f / sg; cw1 = sd * sqdt; icv1 = 1.f / cvv;
        rb2_1 = b2[d]; mb1 = fmaf(cvv, rb2_1, mur1 * DT);
        xsel1 = mur1;
        sMU[cb][d] = mur1;
        sSG[cb][d] = sg;
    }
    __syncthreads();

    // ---- replicated per-chain state
    float xt0 = sMU[cb][0], xt1 = sMU[cb][1], xt2 = sMU[cb][2], xt3 = sMU[cb][3],
          xt4 = sMU[cb][4], xt5 = sMU[cb][5], xt6 = sMU[cb][6], xt7 = sMU[cb][7],
          xt8 = sMU[cb][8], xt9 = sMU[cb][9];
    const float cvt0 = 0.5f * DT * expf(sSG[cb][0]);
    const float cvt1 = 0.5f * DT * expf(sSG[cb][1]);
    const float cvt2 = 0.5f * DT * expf(sSG[cb][2]);
    const float cvt3 = 0.5f * DT * expf(sSG[cb][3]);
    const float cvt4 = 0.5f * DT * expf(sSG[cb][4]);
    const float cvt5 = 0.5f * DT * expf(sSG[cb][5]);
    const float cvt6 = 0.5f * DT * expf(sSG[cb][6]);
    const float cvt7 = 0.5f * DT * expf(sSG[cb][7]);
    const float cvt8 = 0.5f * DT * expf(sSG[cb][8]);
    const float cvt9 = 0.5f * DT * expf(sSG[cb][9]);

    // ---- weights into registers (per-lane slice)
    const int j8 = lane * 8;
    const float4 b1a = *(const float4*)&b1[j8];
    const float4 b1b = *(const float4*)&b1[j8 + 4];

#define DECLW1(k) \
    const float4 w1a##k = *(const float4*)&W1[(k) * HID + j8]; \
    const float4 w1b##k = *(const float4*)&W1[(k) * HID + j8 + 4];
    DECLW1(0) DECLW1(1) DECLW1(2) DECLW1(3) DECLW1(4) DECLW1(5)
    DECLW1(6) DECLW1(7) DECLW1(8) DECLW1(9) DECLW1(10)

    // W2 rows j8..j8+7, each 10 floats, pre-scaled by cv_d
#define DECLW2(q) \
    float4 w2A##q; float4 w2B##q; float2 w2C##q; { \
        const float* r = W2 + (j8 + (q)) * LATENT; \
        float2 p0 = *(const float2*)r,       p1 = *(const float2*)(r + 2); \
        float2 p2 = *(const float2*)(r + 4), p3 = *(const float2*)(r + 6); \
        float2 p4 = *(const float2*)(r + 8); \
        w2A##q = make_float4(p0.x * cvt0, p0.y * cvt1, p1.x * cvt2, p1.y * cvt3); \
        w2B##q = make_float4(p2.x * cvt4, p2.y * cvt5, p3.x * cvt6, p3.y * cvt7); \
        w2C##q = make_float2(p4.x * cvt8, p4.y * cvt9); }
    F8(DECLW2)

    // ownership masks (float 0/1)
    const float mk0 = (lane == 0) ? 1.f : 0.f;
    const float mk1 = (lane == 1) ? 1.f : 0.f;
    const float mk2 = (lane == 2) ? 1.f : 0.f;
    const float mk3 = (lane == 3) ? 1.f : 0.f;
    const float mk4 = (lane == 4) ? 1.f : 0.f;
    const float mk5 = (lane == 5) ? 1.f : 0.f;
    const float mk6 = (lane == 6) ? 1.f : 0.f;
    const float mk7 = (lane == 7) ? 1.f : 0.f;

    // noise pointers: primary d=lane, secondary d=8+lane (lanes>=2 alias primary)
    const float* np0 = noise + ((size_t)l * NSTEPS * BATCH + bb) * LATENT + lane;
    const float* np1 = np0 + (has2 ? 8 : 0);
    float nz0 = np0[0];
    float nz1 = np1[0];

    #pragma unroll 1
    for (int s = 0; s < NSTEPS; ++s) {
        const float cu0 = nz0, cu1 = nz1;
        if (s + 1 < NSTEPS) {
            const size_t off = (size_t)(s + 1) * (BATCH * LATENT);
            nz0 = np0[off];
            nz1 = np1[off];
        }
        const float tt = (float)(l + s) * DT;

        // h = relu([xt, t] @ W1 + b1), lane's 8-unit slice
        float h0 = fmaf(xt0, w1a0.x, b1a.x), h1 = fmaf(xt0, w1a0.y, b1a.y);
        float h2 = fmaf(xt0, w1a0.z, b1a.z), h3 = fmaf(xt0, w1a0.w, b1a.w);
        float h4 = fmaf(xt0, w1b0.x, b1b.x), h5 = fmaf(xt0, w1b0.y, b1b.y);
        float h6 = fmaf(xt0, w1b0.z, b1b.z), h7 = fmaf(xt0, w1b0.w, b1b.w);
        HK(1, xt1) HK(2, xt2) HK(3, xt3) HK(4, xt4) HK(5, xt5)
        HK(6, xt6) HK(7, xt7) HK(8, xt8) HK(9, xt9) HK(10, tt)
        h0 = fmaxf(h0, 0.f); h1 = fmaxf(h1, 0.f); h2 = fmaxf(h2, 0.f); h3 = fmaxf(h3, 0.f);
        h4 = fmaxf(h4, 0.f); h5 = fmaxf(h5, 0.f); h6 = fmaxf(h6, 0.f); h7 = fmaxf(h7, 0.f);

        // partial contributions: ac_d = cv_d * sum_{q in slice} h_q W2[j][d]
        float ac0 = h0 * w2A0.x, ac1 = h0 * w2A0.y, ac2 = h0 * w2A0.z, ac3 = h0 * w2A0.w;
        float ac4 = h0 * w2B0.x, ac5 = h0 * w2B0.y, ac6 = h0 * w2B0.z, ac7 = h0 * w2B0.w;
        float ac8 = h0 * w2C0.x, ac9 = h0 * w2C0.y;
        W2Q(1, h1) W2Q(2, h2) W2Q(3, h3) W2Q(4, h4)
        W2Q(5, h5) W2Q(6, h6) W2Q(7, h7)

        // owner adds its base term: mu*dt + cv*b2 + cw*dW
        const float ob0 = fmaf(cw0, cu0, mb0);
        const float ob1 = fmaf(cw1, cu1, mb1);
        ac0 = fmaf(mk0, ob0, ac0); ac1 = fmaf(mk1, ob0, ac1);
        ac2 = fmaf(mk2, ob0, ac2); ac3 = fmaf(mk3, ob0, ac3);
        ac4 = fmaf(mk4, ob0, ac4); ac5 = fmaf(mk5, ob0, ac5);
        ac6 = fmaf(mk6, ob0, ac6); ac7 = fmaf(mk7, ob0, ac7);
        ac8 = fmaf(mk0, ob1, ac8); ac9 = fmaf(mk1, ob1, ac9);

        // butterfly all-reduce over the 8-lane group -> ac_d = delta_xt_d everywhere
        ac0 = dpp8_allsum(ac0); ac1 = dpp8_allsum(ac1);
        ac2 = dpp8_allsum(ac2); ac3 = dpp8_allsum(ac3);
        ac4 = dpp8_allsum(ac4); ac5 = dpp8_allsum(ac5);
        ac6 = dpp8_allsum(ac6); ac7 = dpp8_allsum(ac7);
        ac8 = dpp8_allsum(ac8); ac9 = dpp8_allsum(ac9);

        // owner extracts its delta via mask dot (no runtime register indexing)
        float ds0 = ac0 * mk0;
        ds0 = fmaf(ac1, mk1, ds0); ds0 = fmaf(ac2, mk2, ds0);
        ds0 = fmaf(ac3, mk3, ds0); ds0 = fmaf(ac4, mk4, ds0);
        ds0 = fmaf(ac5, mk5, ds0); ds0 = fmaf(ac6, mk6, ds0);
        ds0 = fmaf(ac7, mk7, ds0);
        float ds1 = fmaf(ac9, mk1, ac8 * mk0);

        // error accumulation at owner (uses xt_old tracked in xsel)
        {
            const float ld = (mur0 - xsel0) * is0;
            const float sc = fmaf(ds0 - ob0, icv0, rb2_0);
            const float df = ld - sc;
            er0 = fmaf(df, df, er0);
            xsel0 += ds0;
        }
        {
            const float ld = (mur1 - xsel1) * is1;
            const float sc = fmaf(ds1 - ob1, icv1, rb2_1);
            const float df = ld - sc;
            er1 = fmaf(df, df, er1);
            xsel1 += ds1;
        }

        // replicated xt update
        xt0 += ac0; xt1 += ac1; xt2 += ac2; xt3 += ac3; xt4 += ac4;
        xt5 += ac5; xt6 += ac6; xt7 += ac7; xt8 += ac8; xt9 += ac9;
    }

    out[base + lane]          = xsel0;
    out[OUTOFF + base + lane] = er0 * (1.0f / NSTEPS);
    if (has2) {
        out[base + 8 + lane]          = xsel1;
        out[OUTOFF + base + 8 + lane] = er1 * (1.0f / NSTEPS);
    }
}

extern "C" void kernel_launch(void* const* d_in, const int* in_sizes, int n_in,
                              void* d_out, int out_size, void* d_ws, size_t ws_size,
                              hipStream_t stream) {
    const float* z_mean    = (const float*)d_in[0];
    const float* z_log_var = (const float*)d_in[1];
    const float* W1 = (const float*)d_in[2];
    const float* b1 = (const float*)d_in[3];
    const float* W2 = (const float*)d_in[4];
    const float* b2 = (const float*)d_in[5];
    const float* noise = (const float*)d_in[6];
    float* out = (float*)d_out;

    // 40960 chains x 8 lanes = 327680 threads = 1280 blocks of 256
    vae_sde_kernel<<<dim3(1280), dim3(256), 0, stream>>>(
        z_mean, z_log_var, W1, b1, W2, b2, noise, out);
}

// Round 6
// 196.039 us; speedup vs baseline: 51.6963x; 1.1730x over previous
//
#include <hip/hip_runtime.h>
#include <math.h>

#define BATCH 512
#define MAXLEN 80
#define LATENT 10
#define HID 64
#define NSTEPS 100
#define DT 0.01f
#define OUTOFF (BATCH * MAXLEN * LATENT)

typedef float v2f __attribute__((ext_vector_type(2)));

__device__ __forceinline__ v2f mkv(float a, float b) { v2f r; r.x = a; r.y = b; return r; }
__device__ __forceinline__ v2f bc(float a) { v2f r; r.x = a; r.y = a; return r; }
__device__ __forceinline__ v2f fma2(v2f a, v2f b, v2f c) { return __builtin_elementwise_fma(a, b, c); }

template <int CTRL>
__device__ __forceinline__ v2f dppadd(v2f x) {
    v2f t;
    t.x = __int_as_float(__builtin_amdgcn_update_dpp(0, __float_as_int(x.x), CTRL, 0xF, 0xF, false));
    t.y = __int_as_float(__builtin_amdgcn_update_dpp(0, __float_as_int(x.y), CTRL, 0xF, 0xF, false));
    return x + t;   // v_pk_add_f32
}
// all-reduce over 8-lane group: xor1, xor2, mirror(xor7) — same tree as R5
__device__ __forceinline__ v2f allsum(v2f x) {
    x = dppadd<0xB1>(x);    // quad_perm [1,0,3,2]
    x = dppadd<0x4E>(x);    // quad_perm [2,3,0,1]
    x = dppadd<0x141>(x);   // row_half_mirror
    return x;
}

// h-pairs += xk * W1[k][slice]
#define HKP(k, xk) { \
    v2f xb = bc(xk); \
    h01 = fma2(xb, w1_##k##_0, h01); h23 = fma2(xb, w1_##k##_1, h23); \
    h45 = fma2(xb, w1_##k##_2, h45); h67 = fma2(xb, w1_##k##_3, h67); }

// ac-pairs += h_q * w2scaled[q][*]
#define W2P(q, hs) { \
    v2f hb = bc(hs); \
    a01 = fma2(hb, w2_##q##_0, a01); a23 = fma2(hb, w2_##q##_1, a23); \
    a45 = fma2(hb, w2_##q##_2, a45); a67 = fma2(hb, w2_##q##_3, a67); \
    a89 = fma2(hb, w2_##q##_4, a89); }

#define DECLW1(k) \
    v2f w1_##k##_0, w1_##k##_1, w1_##k##_2, w1_##k##_3; { \
        const v2f* r_ = (const v2f*)&W1[(k) * HID + j8]; \
        w1_##k##_0 = r_[0]; w1_##k##_1 = r_[1]; w1_##k##_2 = r_[2]; w1_##k##_3 = r_[3]; }

#define DECLW2(q) \
    v2f w2_##q##_0, w2_##q##_1, w2_##q##_2, w2_##q##_3, w2_##q##_4; { \
        const v2f* r_ = (const v2f*)(W2 + (j8 + (q)) * LATENT); \
        w2_##q##_0 = r_[0] * cvt01; w2_##q##_1 = r_[1] * cvt23; \
        w2_##q##_2 = r_[2] * cvt45; w2_##q##_3 = r_[3] * cvt67; \
        w2_##q##_4 = r_[4] * cvt89; }

#define PIN4(a, b, c, d) asm volatile("" : "+v"(a), "+v"(b), "+v"(c), "+v"(d));

__global__ __launch_bounds__(256, 2) void vae_sde_kernel(
    const float* __restrict__ z_mean, const float* __restrict__ z_log_var,
    const float* __restrict__ W1, const float* __restrict__ b1,
    const float* __restrict__ W2, const float* __restrict__ b2,
    const float* __restrict__ noise, float* __restrict__ out)
{
    __shared__ float sMU[32][LATENT];
    __shared__ float sSG[32][LATENT];

    const int tid  = threadIdx.x;
    const int g    = blockIdx.x * 256 + tid;
    const int c    = g >> 3;
    const int lane = tid & 7;
    const int cb   = tid >> 3;
    const int l    = c >> 9;
    const int bb   = c & 511;
    const int base = (bb * MAXLEN + l) * LATENT;
    const bool lp   = (l > 0);
    const bool has2 = (lane < 2);
    const float sqdt = sqrtf(DT);

    float mur0, is0, cw0, icv0, rb2_0, mb0, er0 = 0.f, xsel0;
    float mur1 = 0.f, is1 = 0.f, cw1 = 0.f, icv1 = 0.f, rb2_1 = 0.f,
          mb1 = 0.f, er1 = 0.f, xsel1 = 0.f;

    {
        const int d = lane;
        float zm  = z_mean[base + d];
        float zmp = lp ? z_mean[base - LATENT + d] : 0.f;
        float zv  = z_log_var[base + d];
        float zvp = lp ? z_log_var[base - LATENT + d] : 0.f;
        float mx  = fmaxf(zv, zvp);
        float sg  = mx + log1pf(expf(-fabsf(zv - zvp)));
        float sd  = expf(0.5f * sg);
        float cvv = 0.5f * DT * sd * sd;
        mur0 = zm - zmp; is0 = 1.f / sg; cw0 = sd * sqdt; icv0 = 1.f / cvv;
        rb2_0 = b2[d]; mb0 = fmaf(cvv, rb2_0, mur0 * DT);
        xsel0 = mur0;
        sMU[cb][d] = mur0;
        sSG[cb][d] = sg;
    }
    if (has2) {
        const int d = 8 + lane;
        float zm  = z_mean[base + d];
        float zmp = lp ? z_mean[base - LATENT + d] : 0.f;
        float zv  = z_log_var[base + d];
        float zvp = lp ? z_log_var[base - LATENT + d] : 0.f;
        float mx  = fmaxf(zv, zvp);
        float sg  = mx + log1pf(expf(-fabsf(zv - zvp)));
        float sd  = expf(0.5f * sg);
        float cvv = 0.5f * DT * sd * sd;
        mur1 = zm - zmp; is1 = 1.f / sg; cw1 = sd * sqdt; icv1 = 1.f / cvv;
        rb2_1 = b2[d]; mb1 = fmaf(cvv, rb2_1, mur1 * DT);
        xsel1 = mur1;
        sMU[cb][d] = mur1;
        sSG[cb][d] = sg;
    }
    __syncthreads();

    // replicated per-chain state (packed pairs)
    v2f xt01 = mkv(sMU[cb][0], sMU[cb][1]);
    v2f xt23 = mkv(sMU[cb][2], sMU[cb][3]);
    v2f xt45 = mkv(sMU[cb][4], sMU[cb][5]);
    v2f xt67 = mkv(sMU[cb][6], sMU[cb][7]);
    v2f xt89 = mkv(sMU[cb][8], sMU[cb][9]);
    const v2f cvt01 = mkv(0.5f * DT * expf(sSG[cb][0]), 0.5f * DT * expf(sSG[cb][1]));
    const v2f cvt23 = mkv(0.5f * DT * expf(sSG[cb][2]), 0.5f * DT * expf(sSG[cb][3]));
    const v2f cvt45 = mkv(0.5f * DT * expf(sSG[cb][4]), 0.5f * DT * expf(sSG[cb][5]));
    const v2f cvt67 = mkv(0.5f * DT * expf(sSG[cb][6]), 0.5f * DT * expf(sSG[cb][7]));
    const v2f cvt89 = mkv(0.5f * DT * expf(sSG[cb][8]), 0.5f * DT * expf(sSG[cb][9]));

    const int j8 = lane * 8;
    v2f b1_0, b1_1, b1_2, b1_3;
    { const v2f* r_ = (const v2f*)&b1[j8]; b1_0 = r_[0]; b1_1 = r_[1]; b1_2 = r_[2]; b1_3 = r_[3]; }

    DECLW1(0) DECLW1(1) DECLW1(2) DECLW1(3) DECLW1(4) DECLW1(5)
    DECLW1(6) DECLW1(7) DECLW1(8) DECLW1(9) DECLW1(10)
    DECLW2(0) DECLW2(1) DECLW2(2) DECLW2(3)
    DECLW2(4) DECLW2(5) DECLW2(6) DECLW2(7)

    // pin weights in VGPRs: opaque redefinition -> no remat, no per-step reload
    PIN4(w1_0_0, w1_0_1, w1_0_2, w1_0_3)   PIN4(w1_1_0, w1_1_1, w1_1_2, w1_1_3)
    PIN4(w1_2_0, w1_2_1, w1_2_2, w1_2_3)   PIN4(w1_3_0, w1_3_1, w1_3_2, w1_3_3)
    PIN4(w1_4_0, w1_4_1, w1_4_2, w1_4_3)   PIN4(w1_5_0, w1_5_1, w1_5_2, w1_5_3)
    PIN4(w1_6_0, w1_6_1, w1_6_2, w1_6_3)   PIN4(w1_7_0, w1_7_1, w1_7_2, w1_7_3)
    PIN4(w1_8_0, w1_8_1, w1_8_2, w1_8_3)   PIN4(w1_9_0, w1_9_1, w1_9_2, w1_9_3)
    PIN4(w1_10_0, w1_10_1, w1_10_2, w1_10_3)
    PIN4(b1_0, b1_1, b1_2, b1_3)
    PIN4(w2_0_0, w2_0_1, w2_0_2, w2_0_3)   PIN4(w2_0_4, w2_1_0, w2_1_1, w2_1_2)
    PIN4(w2_1_3, w2_1_4, w2_2_0, w2_2_1)   PIN4(w2_2_2, w2_2_3, w2_2_4, w2_3_0)
    PIN4(w2_3_1, w2_3_2, w2_3_3, w2_3_4)   PIN4(w2_4_0, w2_4_1, w2_4_2, w2_4_3)
    PIN4(w2_4_4, w2_5_0, w2_5_1, w2_5_2)   PIN4(w2_5_3, w2_5_4, w2_6_0, w2_6_1)
    PIN4(w2_6_2, w2_6_3, w2_6_4, w2_7_0)   PIN4(w2_7_1, w2_7_2, w2_7_3, w2_7_4)

    const v2f mk01 = mkv(lane == 0 ? 1.f : 0.f, lane == 1 ? 1.f : 0.f);
    const v2f mk23 = mkv(lane == 2 ? 1.f : 0.f, lane == 3 ? 1.f : 0.f);
    const v2f mk45 = mkv(lane == 4 ? 1.f : 0.f, lane == 5 ? 1.f : 0.f);
    const v2f mk67 = mkv(lane == 6 ? 1.f : 0.f, lane == 7 ? 1.f : 0.f);
    const v2f mk89 = mk01;   // dims 8,9 owned by lanes 0,1

    const float* np0 = noise + ((size_t)l * NSTEPS * BATCH + bb) * LATENT + lane;
    const float* np1 = np0 + (has2 ? 8 : 0);
    float nz0 = np0[0];
    float nz1 = np1[0];

    const v2f zero2 = mkv(0.f, 0.f);

    #pragma unroll 1
    for (int s = 0; s < NSTEPS; ++s) {
        const float cu0 = nz0, cu1 = nz1;
        if (s + 1 < NSTEPS) {
            const size_t off = (size_t)(s + 1) * (BATCH * LATENT);
            nz0 = np0[off];
            nz1 = np1[off];
        }
        const float tt = (float)(l + s) * DT;

        // h = relu([xt, t] @ W1 + b1) — lane's 8-unit slice, packed
        v2f h01 = fma2(bc(xt01.x), w1_0_0, b1_0);
        v2f h23 = fma2(bc(xt01.x), w1_0_1, b1_1);
        v2f h45 = fma2(bc(xt01.x), w1_0_2, b1_2);
        v2f h67 = fma2(bc(xt01.x), w1_0_3, b1_3);
        HKP(1, xt01.y) HKP(2, xt23.x) HKP(3, xt23.y) HKP(4, xt45.x)
        HKP(5, xt45.y) HKP(6, xt67.x) HKP(7, xt67.y) HKP(8, xt89.x)
        HKP(9, xt89.y) HKP(10, tt)
        h01 = __builtin_elementwise_max(h01, zero2);
        h23 = __builtin_elementwise_max(h23, zero2);
        h45 = __builtin_elementwise_max(h45, zero2);
        h67 = __builtin_elementwise_max(h67, zero2);

        // ac partials: cv_d * (W2 h)_d
        v2f a01 = w2_0_0 * bc(h01.x), a23 = w2_0_1 * bc(h01.x);
        v2f a45 = w2_0_2 * bc(h01.x), a67 = w2_0_3 * bc(h01.x);
        v2f a89 = w2_0_4 * bc(h01.x);
        W2P(1, h01.y) W2P(2, h23.x) W2P(3, h23.y) W2P(4, h45.x)
        W2P(5, h45.y) W2P(6, h67.x) W2P(7, h67.y)

        // owner base term: mu*dt + cv*b2 + cw*dW
        const float ob0 = fmaf(cw0, cu0, mb0);
        const float ob1 = fmaf(cw1, cu1, mb1);
        a01 = fma2(mk01, bc(ob0), a01);
        a23 = fma2(mk23, bc(ob0), a23);
        a45 = fma2(mk45, bc(ob0), a45);
        a67 = fma2(mk67, bc(ob0), a67);
        a89 = fma2(mk89, bc(ob1), a89);

        // 8-lane all-reduce -> a* = delta_xt everywhere
        a01 = allsum(a01); a23 = allsum(a23); a45 = allsum(a45);
        a67 = allsum(a67); a89 = allsum(a89);

        // owner extracts its delta (packed mask dot)
        v2f t = a01 * mk01;
        t = fma2(a23, mk23, t);
        t = fma2(a45, mk45, t);
        t = fma2(a67, mk67, t);
        const float ds0 = t.x + t.y;
        v2f t9 = a89 * mk89;
        const float ds1 = t9.x + t9.y;

        // error accumulation at owner
        {
            const float ld = (mur0 - xsel0) * is0;
            const float sc = fmaf(ds0 - ob0, icv0, rb2_0);
            const float df = ld - sc;
            er0 = fmaf(df, df, er0);
            xsel0 += ds0;
        }
        {
            const float ld = (mur1 - xsel1) * is1;
            const float sc = fmaf(ds1 - ob1, icv1, rb2_1);
            const float df = ld - sc;
            er1 = fmaf(df, df, er1);
            xsel1 += ds1;
        }

        // replicated xt update (packed)
        xt01 += a01; xt23 += a23; xt45 += a45; xt67 += a67; xt89 += a89;
    }

    out[base + lane]          = xsel0;
    out[OUTOFF + base + lane] = er0 * (1.0f / NSTEPS);
    if (has2) {
        out[base + 8 + lane]          = xsel1;
        out[OUTOFF + base + 8 + lane] = er1 * (1.0f / NSTEPS);
    }
}

extern "C" void kernel_launch(void* const* d_in, const int* in_sizes, int n_in,
                              void* d_out, int out_size, void* d_ws, size_t ws_size,
                              hipStream_t stream) {
    const float* z_mean    = (const float*)d_in[0];
    const float* z_log_var = (const float*)d_in[1];
    const float* W1 = (const float*)d_in[2];
    const float* b1 = (const float*)d_in[3];
    const float* W2 = (const float*)d_in[4];
    const float* b2 = (const float*)d_in[5];
    const float* noise = (const float*)d_in[6];
    float* out = (float*)d_out;

    vae_sde_kernel<<<dim3(1280), dim3(256), 0, stream>>>(
        z_mean, z_log_var, W1, b1, W2, b2, noise, out);
}